// Round 1
// baseline (885.729 us; speedup 1.0000x reference)
//
#include <hip/hip_runtime.h>
#include <hip/hip_bf16.h>

// Problem constants (from setup_inputs: x = [2, 1024, 64] fp32)
constexpr int BB = 2;
constexpr int N  = 1024;
constexpr int C  = 64;
constexpr int S  = N * N;          // 1048576 = 2^20
constexpr int KSEL = S / 6;        // 174762 entries set to 1 per batch
constexpr int EQCAP = 2048;

// ---------------------------------------------------------------------------
// K1: per-row prep. One wave (64 lanes) per row (b*N+n); lane = channel c.
// Produces xd (fp64 copy of x), mean, rr = sum(x^2), sinv = 1/std.
__global__ __launch_bounds__(64) void k_prep(const float* __restrict__ x,
                                             double* __restrict__ xd,
                                             double* __restrict__ mean,
                                             double* __restrict__ rr,
                                             double* __restrict__ sinv) {
    int row = blockIdx.x;            // 0 .. BB*N-1
    int c   = threadIdx.x;           // 0 .. 63
    double v = (double)x[row * C + c];

    double s = v;
#pragma unroll
    for (int off = 32; off >= 1; off >>= 1) s += __shfl_xor(s, off);
    double m = s / 64.0;

    double w = v - m;
    double q = w * w;
#pragma unroll
    for (int off = 32; off >= 1; off >>= 1) q += __shfl_xor(q, off);

    double r = v * v;
#pragma unroll
    for (int off = 32; off >= 1; off >>= 1) r += __shfl_xor(r, off);

    xd[row * C + c] = v;
    if (c == 0) {
        mean[row] = m;
        rr[row]   = r;
        sinv[row] = 1.0 / sqrt(q);
    }
}

// ---------------------------------------------------------------------------
// K2: pairwise kernel. 16x16 pair tile per block (256 threads, 1 pair/thread).
// E  = sqrt(r_i + r_j - 2*dot)        (euclidean)
// Ch = max_c |x_i - x_j|              (chebyshev)
// Cc = clip((dot - 64*mi*mj) * sinv_i * sinv_j, -1, 1)   (corrcoef)
__global__ __launch_bounds__(256) void k_pairwise(const double* __restrict__ xd,
                                                  const double* __restrict__ mean,
                                                  const double* __restrict__ rr,
                                                  const double* __restrict__ sinv,
                                                  double* __restrict__ E,
                                                  double* __restrict__ Ch,
                                                  double* __restrict__ Cc) {
    int b  = blockIdx.z;
    int i0 = blockIdx.y * 16;
    int j0 = blockIdx.x * 16;
    __shared__ double xi[16][65];   // stride 65 doubles -> conflict-free banks
    __shared__ double xj[16][65];

    int t  = threadIdx.x;
    int r  = t >> 4;
    int c4 = (t & 15) << 2;
    const double* xb = xd + (size_t)b * N * C;
    {
        const double* pi = xb + (size_t)(i0 + r) * C + c4;
        const double* pj = xb + (size_t)(j0 + r) * C + c4;
        xi[r][c4]   = pi[0]; xi[r][c4+1] = pi[1]; xi[r][c4+2] = pi[2]; xi[r][c4+3] = pi[3];
        xj[r][c4]   = pj[0]; xj[r][c4+1] = pj[1]; xj[r][c4+2] = pj[2]; xj[r][c4+3] = pj[3];
    }
    __syncthreads();

    int ti = t >> 4, tj = t & 15;
    double dot = 0.0, m = 0.0;
#pragma unroll
    for (int c = 0; c < 64; ++c) {
        double a  = xi[ti][c];
        double bq = xj[tj][c];
        double d  = a - bq;
        m = fmax(m, fabs(d));
        dot = fma(a, bq, dot);
    }
    int gi = b * N + i0 + ti;
    int gj = b * N + j0 + tj;
    double d2 = rr[gi] + rr[gj] - 2.0 * dot;
    double e  = (i0 + ti == j0 + tj) ? 0.0 : sqrt(fmax(d2, 0.0));
    double cv = dot - 64.0 * mean[gi] * mean[gj];
    double cc = cv * sinv[gi] * sinv[gj];
    cc = fmin(1.0, fmax(-1.0, cc));

    size_t idx = (size_t)b * S + (size_t)(i0 + ti) * N + (j0 + tj);
    E[idx]  = e;
    Ch[idx] = m;
    Cc[idx] = cc;
}

// ---------------------------------------------------------------------------
// K3: C = scale * A * B^T  (fp64, both row-major NxN). 64x64 tile/block,
// 256 threads, 4x4 accumulators per thread, K-chunk 16.
__global__ __launch_bounds__(256) void k_gemm_nt(const double* __restrict__ A,
                                                 const double* __restrict__ Bm,
                                                 double* __restrict__ Cm,
                                                 double scale) {
    int b = blockIdx.z;
    const double* Ab = A  + (size_t)b * S;
    const double* Bb = Bm + (size_t)b * S;
    double*       Cb = Cm + (size_t)b * S;
    int i0 = blockIdx.y * 64, j0 = blockIdx.x * 64;

    __shared__ double At[64][17];
    __shared__ double Bt[64][17];

    int t  = threadIdx.x;
    int tx = t & 15, ty = t >> 4;
    int lr = t >> 2;             // 0..63
    int lc = (t & 3) << 2;       // 0,4,8,12

    double acc[4][4] = {};
    const double* ap = Ab + (size_t)(i0 + lr) * N + lc;
    const double* bp = Bb + (size_t)(j0 + lr) * N + lc;

    for (int k0 = 0; k0 < N; k0 += 16) {
        double a0 = ap[0], a1 = ap[1], a2 = ap[2], a3 = ap[3];
        double b0 = bp[0], b1 = bp[1], b2 = bp[2], b3 = bp[3];
        ap += 16; bp += 16;
        __syncthreads();
        At[lr][lc] = a0; At[lr][lc+1] = a1; At[lr][lc+2] = a2; At[lr][lc+3] = a3;
        Bt[lr][lc] = b0; Bt[lr][lc+1] = b1; Bt[lr][lc+2] = b2; Bt[lr][lc+3] = b3;
        __syncthreads();
#pragma unroll
        for (int kk = 0; kk < 16; ++kk) {
            double av[4], bv[4];
#pragma unroll
            for (int p = 0; p < 4; ++p) av[p] = At[ty + 16 * p][kk];
#pragma unroll
            for (int q = 0; q < 4; ++q) bv[q] = Bt[tx + 16 * q][kk];
#pragma unroll
            for (int p = 0; p < 4; ++p)
#pragma unroll
                for (int q = 0; q < 4; ++q)
                    acc[p][q] = fma(av[p], bv[q], acc[p][q]);
        }
    }
#pragma unroll
    for (int p = 0; p < 4; ++p)
#pragma unroll
        for (int q = 0; q < 4; ++q)
            Cb[(size_t)(i0 + ty + 16 * p) * N + (j0 + tx + 16 * q)] = acc[p][q] * scale;
}

// ---------------------------------------------------------------------------
// K5: C = A * B (fp64, row-major). Same blocking as above.
__global__ __launch_bounds__(256) void k_gemm_nn(const double* __restrict__ A,
                                                 const double* __restrict__ Bm,
                                                 double* __restrict__ Cm) {
    int b = blockIdx.z;
    const double* Ab = A  + (size_t)b * S;
    const double* Bb = Bm + (size_t)b * S;
    double*       Cb = Cm + (size_t)b * S;
    int i0 = blockIdx.y * 64, j0 = blockIdx.x * 64;

    __shared__ double At[64][17];
    __shared__ double Bt[16][65];

    int t  = threadIdx.x;
    int tx = t & 15, ty = t >> 4;
    int lr = t >> 2,  lc = (t & 3) << 2;    // A tile: 64 rows x 16 k
    int br = t >> 4,  bc = (t & 15) << 2;   // B tile: 16 k rows x 64 cols

    double acc[4][4] = {};
    const double* ap = Ab + (size_t)(i0 + lr) * N + lc;
    const double* bp = Bb + (size_t)br * N + j0 + bc;

    for (int k0 = 0; k0 < N; k0 += 16) {
        double a0 = ap[0], a1 = ap[1], a2 = ap[2], a3 = ap[3];
        double b0 = bp[0], b1 = bp[1], b2 = bp[2], b3 = bp[3];
        ap += 16; bp += (size_t)16 * N;
        __syncthreads();
        At[lr][lc] = a0; At[lr][lc+1] = a1; At[lr][lc+2] = a2; At[lr][lc+3] = a3;
        Bt[br][bc] = b0; Bt[br][bc+1] = b1; Bt[br][bc+2] = b2; Bt[br][bc+3] = b3;
        __syncthreads();
#pragma unroll
        for (int kk = 0; kk < 16; ++kk) {
            double av[4], bv[4];
#pragma unroll
            for (int p = 0; p < 4; ++p) av[p] = At[ty + 16 * p][kk];
#pragma unroll
            for (int q = 0; q < 4; ++q) bv[q] = Bt[kk][tx + 16 * q];
#pragma unroll
            for (int p = 0; p < 4; ++p)
#pragma unroll
                for (int q = 0; q < 4; ++q)
                    acc[p][q] = fma(av[p], bv[q], acc[p][q]);
        }
    }
#pragma unroll
    for (int p = 0; p < 4; ++p)
#pragma unroll
        for (int q = 0; q < 4; ++q)
            Cb[(size_t)(i0 + ty + 16 * p) * N + (j0 + tx + 16 * q)] = acc[p][q];
}

// ---------------------------------------------------------------------------
// K4: fp64 row softmax (1024 elems/row). One block of 256 per row.
__global__ __launch_bounds__(256) void k_softmax(double* __restrict__ L) {
    int row = blockIdx.x;                 // 0 .. BB*N-1
    double* p = L + (size_t)row * N;
    int t = threadIdx.x;
    int wv = t >> 6, ln = t & 63;

    double v[4];
#pragma unroll
    for (int q = 0; q < 4; ++q) v[q] = p[t + 256 * q];

    double mx = fmax(fmax(v[0], v[1]), fmax(v[2], v[3]));
#pragma unroll
    for (int off = 32; off >= 1; off >>= 1) mx = fmax(mx, __shfl_xor(mx, off));
    __shared__ double redm[4];
    if (ln == 0) redm[wv] = mx;
    __syncthreads();
    mx = fmax(fmax(redm[0], redm[1]), fmax(redm[2], redm[3]));

    double s = 0.0;
#pragma unroll
    for (int q = 0; q < 4; ++q) { v[q] = exp(v[q] - mx); s += v[q]; }
#pragma unroll
    for (int off = 32; off >= 1; off >>= 1) s += __shfl_xor(s, off);
    __shared__ double reds[4];
    if (ln == 0) reds[wv] = s;
    __syncthreads();
    s = reds[0] + reds[1] + reds[2] + reds[3];

#pragma unroll
    for (int q = 0; q < 4; ++q) p[t + 256 * q] = v[q] / s;
}

// ---------------------------------------------------------------------------
// Radix-select on the order-preserving uint64 mapping of fp64.
__device__ __forceinline__ unsigned long long d2key(double d) {
    unsigned long long u = (unsigned long long)__double_as_longlong(d);
    return (u & 0x8000000000000000ULL) ? ~u : (u | 0x8000000000000000ULL);
}

// state per batch: st[2b] = prefix/threshold key, st[2b+1] = remaining count
__global__ void k_sel_init(unsigned long long* st) {
    int t = threadIdx.x;
    if (t < BB) { st[2 * t] = 0ULL; st[2 * t + 1] = (unsigned long long)KSEL; }
}

// 512 blocks: 0..255 -> batch 0, 256..511 -> batch 1; 16 elems/thread.
__global__ __launch_bounds__(256) void k_sel_hist(const double* __restrict__ W,
                                                  const unsigned long long* __restrict__ st,
                                                  int* __restrict__ hist, int shift) {
    __shared__ int lh[256];
    int t = threadIdx.x;
    lh[t] = 0;
    __syncthreads();
    int b = blockIdx.x >> 8;
    int base = (blockIdx.x & 255) * 256 + t;
    int hs = (shift + 8) & 63;
    unsigned long long pref = st[2 * b] >> hs;
    const double* Wb = W + (size_t)b * S;
#pragma unroll 4
    for (int it = 0; it < 16; ++it) {
        int s = base + it * 65536;
        unsigned long long key = d2key(Wb[s]);
        bool match = (shift == 56) || ((key >> hs) == pref);
        if (match) atomicAdd(&lh[(int)((key >> shift) & 255ULL)], 1);
    }
    __syncthreads();
    atomicAdd(&hist[b * 256 + t], lh[t]);
}

__global__ void k_sel_scan(unsigned long long* st, const int* __restrict__ hist, int shift) {
    int b = threadIdx.x;
    if (b >= BB) return;
    unsigned long long kneed = st[2 * b + 1];
    unsigned long long cum = 0;
    int bucket = 0;
    for (int i = 255; i >= 0; --i) {
        unsigned long long h = (unsigned long long)hist[b * 256 + i];
        if (cum + h >= kneed) { bucket = i; break; }
        cum += h;
    }
    st[2 * b] |= ((unsigned long long)bucket) << shift;
    st[2 * b + 1] = kneed - cum;
}

// Collect flat indices of elements exactly equal to threshold key.
__global__ __launch_bounds__(256) void k_sel_eq(const double* __restrict__ W,
                                                const unsigned long long* __restrict__ st,
                                                int* __restrict__ eqbuf) {
    int gid = blockIdx.x * 256 + threadIdx.x;
    int b = gid >> 20;
    int s = gid & (S - 1);
    unsigned long long key = d2key(W[(size_t)b * S + s]);
    if (key == st[2 * b]) {
        int p = atomicAdd(&eqbuf[b * (EQCAP + 1)], 1);
        if (p < EQCAP) eqbuf[b * (EQCAP + 1) + 1 + p] = s;
    }
}

// mask = 1 for key > T; among key == T, the kneed largest flat indices win
// (matches stable argsort(argsort) rank semantics of the reference).
__global__ __launch_bounds__(256) void k_sel_mask(const double* __restrict__ W,
                                                  const unsigned long long* __restrict__ st,
                                                  const int* __restrict__ eqbuf,
                                                  float* __restrict__ out) {
    int gid = blockIdx.x * 256 + threadIdx.x;
    int b = gid >> 20;
    int s = gid & (S - 1);
    unsigned long long T = st[2 * b];
    unsigned long long key = d2key(W[(size_t)b * S + s]);
    float v = 0.0f;
    if (key > T) {
        v = 1.0f;
    } else if (key == T) {
        int cnt = eqbuf[b * (EQCAP + 1)];
        if (cnt > EQCAP) cnt = EQCAP;
        int higher = 0;
        for (int e = 0; e < cnt; ++e) higher += (eqbuf[b * (EQCAP + 1) + 1 + e] > s) ? 1 : 0;
        unsigned long long kneed = st[2 * b + 1];
        v = ((unsigned long long)higher < kneed) ? 1.0f : 0.0f;
    }
    out[(size_t)b * S + s] = v;
}

// ---------------------------------------------------------------------------
extern "C" void kernel_launch(void* const* d_in, const int* in_sizes, int n_in,
                              void* d_out, int out_size, void* d_ws, size_t ws_size,
                              hipStream_t stream) {
    const float* x = (const float*)d_in[0];
    float* out = (float*)d_out;

    char* ws = (char*)d_ws;
    size_t off = 0;
    auto alloc = [&](size_t bytes) -> void* {
        void* p = ws + off;
        off += (bytes + 255) & ~(size_t)255;
        return p;
    };

    double* xd   = (double*)alloc((size_t)BB * N * C * sizeof(double));   // 1 MB
    double* mean = (double*)alloc((size_t)BB * N * sizeof(double));
    double* rr   = (double*)alloc((size_t)BB * N * sizeof(double));
    double* sinv = (double*)alloc((size_t)BB * N * sizeof(double));
    double* E    = (double*)alloc((size_t)BB * S * sizeof(double));       // 16 MB
    double* Ch   = (double*)alloc((size_t)BB * S * sizeof(double));       // 16 MB
    double* Cc   = (double*)alloc((size_t)BB * S * sizeof(double));       // 16 MB
    double* L    = (double*)alloc((size_t)BB * S * sizeof(double));       // 16 MB
    double* W    = E;  // E is dead after gemm_nt -> reuse for weighted
    unsigned long long* st = (unsigned long long*)alloc(64);
    int* hist  = (int*)alloc((size_t)BB * 256 * sizeof(int));
    int* eqbuf = (int*)alloc((size_t)BB * (EQCAP + 1) * sizeof(int));

    // 1) per-row stats + fp64 upconvert
    k_prep<<<BB * N, 64, 0, stream>>>(x, xd, mean, rr, sinv);

    // 2) pairwise adjacencies
    k_pairwise<<<dim3(N / 16, N / 16, BB), 256, 0, stream>>>(xd, mean, rr, sinv, E, Ch, Cc);

    // 3) logits = (E @ Ch^T) * 1/8
    k_gemm_nt<<<dim3(N / 64, N / 64, BB), 256, 0, stream>>>(E, Ch, L, 0.125);

    // 4) softmax rows
    k_softmax<<<BB * N, 256, 0, stream>>>(L);

    // 5) weighted = attn @ Cc   (writes into W == E buffer)
    k_gemm_nn<<<dim3(N / 64, N / 64, BB), 256, 0, stream>>>(L, Cc, W);

    // 6) exact top-K threshold per batch: 8-pass radix select (MSB first)
    k_sel_init<<<1, 64, 0, stream>>>(st);
    for (int pass = 0; pass < 8; ++pass) {
        int shift = 56 - 8 * pass;
        hipMemsetAsync(hist, 0, (size_t)BB * 256 * sizeof(int), stream);
        k_sel_hist<<<512, 256, 0, stream>>>(W, st, hist, shift);
        k_sel_scan<<<1, 64, 0, stream>>>(st, hist, shift);
    }

    // 7) tie resolution + final mask
    hipMemsetAsync(eqbuf, 0, (size_t)BB * (EQCAP + 1) * sizeof(int), stream);
    k_sel_eq<<<(BB * S) / 256, 256, 0, stream>>>(W, st, eqbuf);
    k_sel_mask<<<(BB * S) / 256, 256, 0, stream>>>(W, st, eqbuf, out);
}